// Round 2
// baseline (1514.203 us; speedup 1.0000x reference)
//
#include <hip/hip_runtime.h>
#include <math.h>

#define N_USERS_C 100000
#define N_ITEMS_C 50000
#define N_NODES_C 150000
#define N_EDGES_C 2000000
#define N_ENTRIES_C 4000000   // 2 CSR entries per edge
#define DIM_C 64
#define DECAY_C 1e-4f
#define BATCH_C 4096

// scan geometry: 256 threads x 8 elements = 2048 per block
#define SCAN_ELEMS 2048
#define SCAN_NB ((N_NODES_C + SCAN_ELEMS - 1) / SCAN_ELEMS)  // 74

// ---------------------------------------------------------------------------
// ws layout (in 4-byte units)
//   cnt[150016] | off[150032] | cursor[150016] | bsum[256] | acc[16] |
//   csr_src[4M] | csr_val[4M]
// ---------------------------------------------------------------------------
#define WS_CNT 0
#define WS_OFF 150016
#define WS_CUR 300048
#define WS_BSUM 450064
#define WS_ACC 450320
#define WS_SRC 450336
#define WS_VAL (WS_SRC + N_ENTRIES_C)

// ---------------------------------------------------------------------------
// Kernel 1: histogram of destination degrees.
// dest id: user r -> r ; item c -> N_USERS + c
// ---------------------------------------------------------------------------
__global__ __launch_bounds__(256) void hist_kernel(
    const int* __restrict__ edge_row, const int* __restrict__ edge_col,
    int* __restrict__ cnt) {
  int e = blockIdx.x * blockDim.x + threadIdx.x;
  if (e >= N_EDGES_C) return;
  atomicAdd(&cnt[edge_row[e]], 1);
  atomicAdd(&cnt[N_USERS_C + edge_col[e]], 1);
}

// ---------------------------------------------------------------------------
// Kernel 2a: per-block exclusive scan (2048 elements/block)
// ---------------------------------------------------------------------------
__global__ __launch_bounds__(256) void scan1_kernel(
    const int* __restrict__ cnt, int* __restrict__ off, int* __restrict__ bsum) {
  __shared__ int ts[256];
  const int tid = threadIdx.x;
  const int base = blockIdx.x * SCAN_ELEMS + tid * 8;
  int v[8];
  int s = 0;
  #pragma unroll
  for (int i = 0; i < 8; ++i) {
    int idx = base + i;
    int c = (idx < N_NODES_C) ? cnt[idx] : 0;
    v[i] = s;
    s += c;
  }
  ts[tid] = s;
  __syncthreads();
  // Hillis-Steele inclusive scan over 256 thread totals
  #pragma unroll
  for (int o = 1; o < 256; o <<= 1) {
    int y = (tid >= o) ? ts[tid - o] : 0;
    __syncthreads();
    ts[tid] += y;
    __syncthreads();
  }
  const int exclT = ts[tid] - s;  // exclusive offset of this thread in block
  #pragma unroll
  for (int i = 0; i < 8; ++i) {
    int idx = base + i;
    if (idx < N_NODES_C) off[idx] = exclT + v[i];
  }
  if (tid == 255) bsum[blockIdx.x] = ts[255];
}

// Kernel 2b: exclusive scan of the 74 block sums (trivial, single thread)
__global__ void scan2_kernel(int* __restrict__ bsum) {
  if (threadIdx.x == 0 && blockIdx.x == 0) {
    int s = 0;
    for (int i = 0; i < SCAN_NB; ++i) {
      int t = bsum[i];
      bsum[i] = s;
      s += t;
    }
  }
}

// Kernel 2c: add block offsets; produce final off[] and cursor[] copy
__global__ __launch_bounds__(256) void scan3_kernel(
    int* __restrict__ off, int* __restrict__ cursor,
    const int* __restrict__ bsum) {
  const int base = blockIdx.x * SCAN_ELEMS + threadIdx.x * 8;
  const int add = bsum[blockIdx.x];
  #pragma unroll
  for (int i = 0; i < 8; ++i) {
    int idx = base + i;
    if (idx < N_NODES_C) {
      int o = off[idx] + add;
      off[idx] = o;
      cursor[idx] = o;
    }
  }
  if (blockIdx.x == 0 && threadIdx.x == 0) off[N_NODES_C] = N_ENTRIES_C;
}

// ---------------------------------------------------------------------------
// Kernel 3: bucket-scatter edges into CSR (src index + value per entry).
// For user dest n<N_USERS: src stored is the ITEM index c (0..49999).
// For item dest: src stored is the USER index r.
// ---------------------------------------------------------------------------
__global__ __launch_bounds__(256) void csr_scatter_kernel(
    const int* __restrict__ edge_row, const int* __restrict__ edge_col,
    const float* __restrict__ edge_val, int* __restrict__ cursor,
    int* __restrict__ csr_src, float* __restrict__ csr_val) {
  int e = blockIdx.x * blockDim.x + threadIdx.x;
  if (e >= N_EDGES_C) return;
  int r = edge_row[e];
  int c = edge_col[e];
  float v = edge_val[e];
  int p1 = atomicAdd(&cursor[r], 1);
  csr_src[p1] = c;
  csr_val[p1] = v;
  int p2 = atomicAdd(&cursor[N_USERS_C + c], 1);
  csr_src[p2] = r;
  csr_val[p2] = v;
}

// ---------------------------------------------------------------------------
// Kernel 4: fused gather + transform. One wave handles 2 consecutive nodes:
// register-accumulate agg row (lane = dim), then 3x (W matmul + leakyrelu +
// l2norm) with W staged in LDS; writes ego + 3 layers straight to out.
// ---------------------------------------------------------------------------
__global__ __launch_bounds__(256) void gather_transform_kernel(
    const float* __restrict__ user_emb, const float* __restrict__ item_emb,
    const float* __restrict__ W, const float* __restrict__ b,
    const int* __restrict__ off, const int* __restrict__ csr_src,
    const float* __restrict__ csr_val, float* __restrict__ out) {
  __shared__ float Ws[3 * DIM_C * DIM_C];  // 48 KB
  __shared__ float bs[3 * DIM_C];
  __shared__ float aggS[4][2][DIM_C];

  for (int i = threadIdx.x; i < 3 * DIM_C * DIM_C; i += 256) Ws[i] = W[i];
  for (int i = threadIdx.x; i < 3 * DIM_C; i += 256) bs[i] = b[i];
  __syncthreads();

  const int wave = threadIdx.x >> 6;
  const int lane = threadIdx.x & 63;
  const int pairsTotal = N_NODES_C / 2;  // 75000

  for (int p = blockIdx.x * 4 + wave; p < pairsTotal; p += gridDim.x * 4) {
    const int n0 = 2 * p;
    const int n1 = n0 + 1;

    // ---- gather agg rows into registers (lane = dim) ----
    float a0 = 0.f, a1 = 0.f;
    {
      const float* base0 = (n0 < N_USERS_C) ? item_emb : user_emb;
      int i = off[n0];
      const int e0 = off[n0 + 1];
      for (; i + 4 <= e0; i += 4) {
        int sA = csr_src[i], sB = csr_src[i + 1], sC = csr_src[i + 2], sD = csr_src[i + 3];
        float vA = csr_val[i], vB = csr_val[i + 1], vC = csr_val[i + 2], vD = csr_val[i + 3];
        float rA = base0[(size_t)sA * DIM_C + lane];
        float rB = base0[(size_t)sB * DIM_C + lane];
        float rC = base0[(size_t)sC * DIM_C + lane];
        float rD = base0[(size_t)sD * DIM_C + lane];
        a0 += vA * rA + vB * rB + vC * rC + vD * rD;
      }
      for (; i < e0; ++i) a0 += csr_val[i] * base0[(size_t)csr_src[i] * DIM_C + lane];

      const float* base1 = (n1 < N_USERS_C) ? item_emb : user_emb;
      i = off[n1];
      const int e1 = off[n1 + 1];
      for (; i + 4 <= e1; i += 4) {
        int sA = csr_src[i], sB = csr_src[i + 1], sC = csr_src[i + 2], sD = csr_src[i + 3];
        float vA = csr_val[i], vB = csr_val[i + 1], vC = csr_val[i + 2], vD = csr_val[i + 3];
        float rA = base1[(size_t)sA * DIM_C + lane];
        float rB = base1[(size_t)sB * DIM_C + lane];
        float rC = base1[(size_t)sC * DIM_C + lane];
        float rD = base1[(size_t)sD * DIM_C + lane];
        a1 += vA * rA + vB * rB + vC * rC + vD * rD;
      }
      for (; i < e1; ++i) a1 += csr_val[i] * base1[(size_t)csr_src[i] * DIM_C + lane];
    }

    aggS[wave][0][lane] = a0;
    aggS[wave][1][lane] = a1;

    // ---- ego columns ----
    float e0v = (n0 < N_USERS_C) ? user_emb[(size_t)n0 * DIM_C + lane]
                                 : item_emb[(size_t)(n0 - N_USERS_C) * DIM_C + lane];
    float e1v = (n1 < N_USERS_C) ? user_emb[(size_t)n1 * DIM_C + lane]
                                 : item_emb[(size_t)(n1 - N_USERS_C) * DIM_C + lane];
    out[1 + (size_t)n0 * 256 + lane] = e0v;
    out[1 + (size_t)n1 * 256 + lane] = e1v;

    // ---- 3 layers: s = agg @ W[l] + b[l]; leakyrelu; l2norm ----
    for (int l = 0; l < 3; ++l) {
      float s0 = bs[l * DIM_C + lane];
      float s1 = s0;
      const float* Wl = &Ws[l * DIM_C * DIM_C];
      #pragma unroll
      for (int k = 0; k < DIM_C; k += 4) {
        float4 q0 = *(const float4*)&aggS[wave][0][k];  // broadcast
        float4 q1 = *(const float4*)&aggS[wave][1][k];
        float w0 = Wl[(k + 0) * DIM_C + lane];
        float w1 = Wl[(k + 1) * DIM_C + lane];
        float w2 = Wl[(k + 2) * DIM_C + lane];
        float w3 = Wl[(k + 3) * DIM_C + lane];
        s0 += q0.x * w0 + q0.y * w1 + q0.z * w2 + q0.w * w3;
        s1 += q1.x * w0 + q1.y * w1 + q1.z * w2 + q1.w * w3;
      }
      s0 = (s0 >= 0.f) ? s0 : 0.2f * s0;
      s1 = (s1 >= 0.f) ? s1 : 0.2f * s1;
      float t0 = s0 * s0, t1 = s1 * s1;
      #pragma unroll
      for (int o = 32; o; o >>= 1) {
        t0 += __shfl_xor(t0, o);
        t1 += __shfl_xor(t1, o);
      }
      out[1 + (size_t)n0 * 256 + (size_t)(l + 1) * 64 + lane] =
          s0 / fmaxf(sqrtf(t0), 1e-12f);
      out[1 + (size_t)n1 * 256 + (size_t)(l + 1) * 64 + lane] =
          s1 / fmaxf(sqrtf(t1), 1e-12f);
    }
  }
}

// ---------------------------------------------------------------------------
// Kernel 5: BPR loss. One wave per batch element.
// ---------------------------------------------------------------------------
__global__ __launch_bounds__(256) void loss_kernel(
    const float* __restrict__ out, const int* __restrict__ bu,
    const int* __restrict__ bp, const int* __restrict__ bn,
    float* __restrict__ acc) {
  const int wave = threadIdx.x >> 6;
  const int lane = threadIdx.x & 63;
  const int j = blockIdx.x * 4 + wave;
  if (j >= BATCH_C) return;

  const float* urow = out + 1 + (size_t)bu[j] * 256;
  const float* prow = out + 1 + ((size_t)N_USERS_C + bp[j]) * 256;
  const float* nrow = out + 1 + ((size_t)N_USERS_C + bn[j]) * 256;

  float4 u = ((const float4*)urow)[lane];
  float4 pp = ((const float4*)prow)[lane];
  float4 nn = ((const float4*)nrow)[lane];

  float x = u.x * (pp.x - nn.x) + u.y * (pp.y - nn.y) +
            u.z * (pp.z - nn.z) + u.w * (pp.w - nn.w);
  float r = u.x * u.x + u.y * u.y + u.z * u.z + u.w * u.w +
            pp.x * pp.x + pp.y * pp.y + pp.z * pp.z + pp.w * pp.w +
            nn.x * nn.x + nn.y * nn.y + nn.z * nn.z + nn.w * nn.w;

  #pragma unroll
  for (int o = 32; o; o >>= 1) {
    x += __shfl_xor(x, o);
    r += __shfl_xor(r, o);
  }
  if (lane == 0) {
    float ls = fminf(x, 0.f) - log1pf(expf(-fabsf(x)));
    atomicAdd(&acc[0], -ls);
    atomicAdd(&acc[1], 0.5f * r);
  }
}

__global__ void finalize_kernel(const float* __restrict__ acc,
                                float* __restrict__ out) {
  out[0] = acc[0] / (float)BATCH_C + DECAY_C * acc[1] / (float)BATCH_C;
}

// ---------------------------------------------------------------------------
extern "C" void kernel_launch(void* const* d_in, const int* in_sizes, int n_in,
                              void* d_out, int out_size, void* d_ws, size_t ws_size,
                              hipStream_t stream) {
  const float* user_emb = (const float*)d_in[0];
  const float* item_emb = (const float*)d_in[1];
  const float* edge_val = (const float*)d_in[2];
  const float* W        = (const float*)d_in[3];
  const float* b        = (const float*)d_in[4];
  const int* edge_row   = (const int*)d_in[5];
  const int* edge_col   = (const int*)d_in[6];
  const int* bu         = (const int*)d_in[7];
  const int* bp         = (const int*)d_in[8];
  const int* bn         = (const int*)d_in[9];

  float* out = (float*)d_out;
  int* ws = (int*)d_ws;
  int*   cnt     = ws + WS_CNT;
  int*   off     = ws + WS_OFF;
  int*   cursor  = ws + WS_CUR;
  int*   bsum    = ws + WS_BSUM;
  float* acc     = (float*)(ws + WS_ACC);
  int*   csr_src = ws + WS_SRC;
  float* csr_val = (float*)(ws + WS_VAL);

  // zero the histogram counters and the loss accumulators
  hipMemsetAsync(cnt, 0, 150016 * sizeof(int), stream);
  hipMemsetAsync(acc, 0, 2 * sizeof(float), stream);

  hist_kernel<<<(N_EDGES_C + 255) / 256, 256, 0, stream>>>(edge_row, edge_col, cnt);
  scan1_kernel<<<SCAN_NB, 256, 0, stream>>>(cnt, off, bsum);
  scan2_kernel<<<1, 64, 0, stream>>>(bsum);
  scan3_kernel<<<SCAN_NB, 256, 0, stream>>>(off, cursor, bsum);
  csr_scatter_kernel<<<(N_EDGES_C + 255) / 256, 256, 0, stream>>>(
      edge_row, edge_col, edge_val, cursor, csr_src, csr_val);
  gather_transform_kernel<<<4096, 256, 0, stream>>>(
      user_emb, item_emb, W, b, off, csr_src, csr_val, out);
  loss_kernel<<<BATCH_C / 4, 256, 0, stream>>>(out, bu, bp, bn, acc);
  finalize_kernel<<<1, 1, 0, stream>>>(acc, out);
}

// Round 3
// 893.031 us; speedup vs baseline: 1.6956x; 1.6956x over previous
//
#include <hip/hip_runtime.h>
#include <math.h>

#define N_USERS_C 100000
#define N_ITEMS_C 50000
#define N_NODES_C 150000
#define N_EDGES_C 2000000
#define N_ENTRIES_C 4000000   // 2 CSR entries per edge
#define DIM_C 64
#define DECAY_C 1e-4f
#define BATCH_C 4096

// scan geometry: 256 threads x 8 elements = 2048 per block
#define SCAN_ELEMS 2048
#define SCAN_NB ((N_NODES_C + SCAN_ELEMS - 1) / SCAN_ELEMS)  // 74

// ---------------------------------------------------------------------------
// ws layout (in 4-byte units)
//   cnt[150016] | off[150032] | cursor[150016] | bsum[256] | acc[16] |
//   csr[4M x int2]
// ---------------------------------------------------------------------------
#define WS_CNT 0
#define WS_OFF 150016
#define WS_CUR 300048
#define WS_BSUM 450064
#define WS_ACC 450320
#define WS_CSR 450336   // byte offset 1801344, 8B aligned

// ---------------------------------------------------------------------------
// Kernel 1: histogram of destination degrees.
// ---------------------------------------------------------------------------
__global__ __launch_bounds__(256) void hist_kernel(
    const int* __restrict__ edge_row, const int* __restrict__ edge_col,
    int* __restrict__ cnt) {
  int e = blockIdx.x * blockDim.x + threadIdx.x;
  if (e >= N_EDGES_C) return;
  atomicAdd(&cnt[edge_row[e]], 1);
  atomicAdd(&cnt[N_USERS_C + edge_col[e]], 1);
}

// ---------------------------------------------------------------------------
// Kernel 2a: per-block exclusive scan (2048 elements/block)
// ---------------------------------------------------------------------------
__global__ __launch_bounds__(256) void scan1_kernel(
    const int* __restrict__ cnt, int* __restrict__ off, int* __restrict__ bsum) {
  __shared__ int ts[256];
  const int tid = threadIdx.x;
  const int base = blockIdx.x * SCAN_ELEMS + tid * 8;
  int v[8];
  int s = 0;
  #pragma unroll
  for (int i = 0; i < 8; ++i) {
    int idx = base + i;
    int c = (idx < N_NODES_C) ? cnt[idx] : 0;
    v[i] = s;
    s += c;
  }
  ts[tid] = s;
  __syncthreads();
  #pragma unroll
  for (int o = 1; o < 256; o <<= 1) {
    int y = (tid >= o) ? ts[tid - o] : 0;
    __syncthreads();
    ts[tid] += y;
    __syncthreads();
  }
  const int exclT = ts[tid] - s;
  #pragma unroll
  for (int i = 0; i < 8; ++i) {
    int idx = base + i;
    if (idx < N_NODES_C) off[idx] = exclT + v[i];
  }
  if (tid == 255) bsum[blockIdx.x] = ts[255];
}

__global__ void scan2_kernel(int* __restrict__ bsum) {
  if (threadIdx.x == 0 && blockIdx.x == 0) {
    int s = 0;
    for (int i = 0; i < SCAN_NB; ++i) {
      int t = bsum[i];
      bsum[i] = s;
      s += t;
    }
  }
}

__global__ __launch_bounds__(256) void scan3_kernel(
    int* __restrict__ off, int* __restrict__ cursor,
    const int* __restrict__ bsum) {
  const int base = blockIdx.x * SCAN_ELEMS + threadIdx.x * 8;
  const int add = bsum[blockIdx.x];
  #pragma unroll
  for (int i = 0; i < 8; ++i) {
    int idx = base + i;
    if (idx < N_NODES_C) {
      int o = off[idx] + add;
      off[idx] = o;
      cursor[idx] = o;
    }
  }
  if (blockIdx.x == 0 && threadIdx.x == 0) off[N_NODES_C] = N_ENTRIES_C;
}

// ---------------------------------------------------------------------------
// Kernel 3: bucket-scatter edges into CSR as packed int2 (src, val bits).
// ---------------------------------------------------------------------------
__global__ __launch_bounds__(256) void csr_scatter_kernel(
    const int* __restrict__ edge_row, const int* __restrict__ edge_col,
    const float* __restrict__ edge_val, int* __restrict__ cursor,
    int2* __restrict__ csr) {
  int e = blockIdx.x * blockDim.x + threadIdx.x;
  if (e >= N_EDGES_C) return;
  int r = edge_row[e];
  int c = edge_col[e];
  int vb = __float_as_int(edge_val[e]);
  int p1 = atomicAdd(&cursor[r], 1);
  csr[p1] = make_int2(c, vb);
  int p2 = atomicAdd(&cursor[N_USERS_C + c], 1);
  csr[p2] = make_int2(r, vb);
}

// ---------------------------------------------------------------------------
// Kernel 4: fused gather + transform.
// Block = 32 nodes (8 per wave). Gather: quarter-wave (16 lanes x float4)
// handles one CSR entry -> 4 rows in flight per wave, unroll x2 -> 8.
// Transform: W staged per layer (16 KB LDS), 8 acc per wave, broadcast agg.
// ---------------------------------------------------------------------------
__global__ __launch_bounds__(256) void fused_kernel(
    const float* __restrict__ user_emb, const float* __restrict__ item_emb,
    const float* __restrict__ W, const float* __restrict__ b,
    const int* __restrict__ off, const int2* __restrict__ csr,
    float* __restrict__ out) {
  __shared__ float Wl[DIM_C * DIM_C];      // 16 KB, one layer at a time
  __shared__ float aggS[32][DIM_C];        // 8 KB

  const int tid = threadIdx.x;
  const int wave = tid >> 6;
  const int lane = tid & 63;
  const int quarter = lane >> 4;
  const int ql = lane & 15;
  const int nodeBase = blockIdx.x * 32;

  // ---- gather phase: each wave accumulates 8 nodes ----
  #pragma unroll 1
  for (int j = 0; j < 8; ++j) {
    const int n = nodeBase + wave * 8 + j;
    if (n < N_NODES_C) {
      const float* __restrict__ src = (n < N_USERS_C) ? item_emb : user_emb;
      const int end = off[n + 1];
      int i = off[n] + quarter;
      float4 acc = make_float4(0.f, 0.f, 0.f, 0.f);
      // two entries in flight per quarter
      for (; i + 4 < end; i += 8) {
        int2 e0 = csr[i];
        int2 e1 = csr[i + 4];
        const float4 r0 = *(const float4*)&src[(size_t)e0.x * DIM_C + ql * 4];
        const float4 r1 = *(const float4*)&src[(size_t)e1.x * DIM_C + ql * 4];
        const float v0 = __int_as_float(e0.y);
        const float v1 = __int_as_float(e1.y);
        acc.x += v0 * r0.x + v1 * r1.x;
        acc.y += v0 * r0.y + v1 * r1.y;
        acc.z += v0 * r0.z + v1 * r1.z;
        acc.w += v0 * r0.w + v1 * r1.w;
      }
      if (i < end) {
        int2 e0 = csr[i];
        const float4 r0 = *(const float4*)&src[(size_t)e0.x * DIM_C + ql * 4];
        const float v0 = __int_as_float(e0.y);
        acc.x += v0 * r0.x;
        acc.y += v0 * r0.y;
        acc.z += v0 * r0.z;
        acc.w += v0 * r0.w;
      }
      // combine the 4 quarters
      acc.x += __shfl_xor(acc.x, 16); acc.x += __shfl_xor(acc.x, 32);
      acc.y += __shfl_xor(acc.y, 16); acc.y += __shfl_xor(acc.y, 32);
      acc.z += __shfl_xor(acc.z, 16); acc.z += __shfl_xor(acc.z, 32);
      acc.w += __shfl_xor(acc.w, 16); acc.w += __shfl_xor(acc.w, 32);
      if (lane < 16) *(float4*)&aggS[wave * 8 + j][ql * 4] = acc;

      // ego columns while we're here (independent of aggS)
      const float ego = (n < N_USERS_C)
                            ? user_emb[(size_t)n * DIM_C + lane]
                            : item_emb[(size_t)(n - N_USERS_C) * DIM_C + lane];
      out[1 + (size_t)n * 256 + lane] = ego;
    }
  }

  // ---- transform phase: 3 layers, W staged per layer ----
  for (int l = 0; l < 3; ++l) {
    __syncthreads();  // previous layer's Wl no longer in use / aggS ready
    {
      const float4* Wg = (const float4*)(W + l * DIM_C * DIM_C);
      float4* Wd = (float4*)Wl;
      #pragma unroll
      for (int i = 0; i < 4; ++i) Wd[tid + i * 256] = Wg[tid + i * 256];
    }
    __syncthreads();

    const float bias = b[l * DIM_C + lane];
    float acc[8];
    #pragma unroll
    for (int j = 0; j < 8; ++j) acc[j] = bias;

    #pragma unroll 4
    for (int k4 = 0; k4 < 16; ++k4) {
      const float w0 = Wl[(k4 * 4 + 0) * DIM_C + lane];
      const float w1 = Wl[(k4 * 4 + 1) * DIM_C + lane];
      const float w2 = Wl[(k4 * 4 + 2) * DIM_C + lane];
      const float w3 = Wl[(k4 * 4 + 3) * DIM_C + lane];
      #pragma unroll
      for (int j = 0; j < 8; ++j) {
        const float4 a = *(const float4*)&aggS[wave * 8 + j][k4 * 4];  // broadcast
        acc[j] += a.x * w0 + a.y * w1 + a.z * w2 + a.w * w3;
      }
    }

    #pragma unroll
    for (int j = 0; j < 8; ++j) {
      const int n = nodeBase + wave * 8 + j;
      float s = acc[j];
      s = (s >= 0.f) ? s : 0.2f * s;
      float q = s * s;
      #pragma unroll
      for (int o = 32; o; o >>= 1) q += __shfl_xor(q, o);
      if (n < N_NODES_C)
        out[1 + (size_t)n * 256 + (size_t)(l + 1) * 64 + lane] =
            s / fmaxf(sqrtf(q), 1e-12f);
    }
  }
}

// ---------------------------------------------------------------------------
// Kernel 5: BPR loss. One wave per batch element.
// ---------------------------------------------------------------------------
__global__ __launch_bounds__(256) void loss_kernel(
    const float* __restrict__ out, const int* __restrict__ bu,
    const int* __restrict__ bp, const int* __restrict__ bn,
    float* __restrict__ acc) {
  const int wave = threadIdx.x >> 6;
  const int lane = threadIdx.x & 63;
  const int j = blockIdx.x * 4 + wave;
  if (j >= BATCH_C) return;

  const float* urow = out + 1 + (size_t)bu[j] * 256;
  const float* prow = out + 1 + ((size_t)N_USERS_C + bp[j]) * 256;
  const float* nrow = out + 1 + ((size_t)N_USERS_C + bn[j]) * 256;

  float4 u = ((const float4*)urow)[lane];
  float4 pp = ((const float4*)prow)[lane];
  float4 nn = ((const float4*)nrow)[lane];

  float x = u.x * (pp.x - nn.x) + u.y * (pp.y - nn.y) +
            u.z * (pp.z - nn.z) + u.w * (pp.w - nn.w);
  float r = u.x * u.x + u.y * u.y + u.z * u.z + u.w * u.w +
            pp.x * pp.x + pp.y * pp.y + pp.z * pp.z + pp.w * pp.w +
            nn.x * nn.x + nn.y * nn.y + nn.z * nn.z + nn.w * nn.w;

  #pragma unroll
  for (int o = 32; o; o >>= 1) {
    x += __shfl_xor(x, o);
    r += __shfl_xor(r, o);
  }
  if (lane == 0) {
    float ls = fminf(x, 0.f) - log1pf(expf(-fabsf(x)));
    atomicAdd(&acc[0], -ls);
    atomicAdd(&acc[1], 0.5f * r);
  }
}

__global__ void finalize_kernel(const float* __restrict__ acc,
                                float* __restrict__ out) {
  out[0] = acc[0] / (float)BATCH_C + DECAY_C * acc[1] / (float)BATCH_C;
}

// ---------------------------------------------------------------------------
extern "C" void kernel_launch(void* const* d_in, const int* in_sizes, int n_in,
                              void* d_out, int out_size, void* d_ws, size_t ws_size,
                              hipStream_t stream) {
  const float* user_emb = (const float*)d_in[0];
  const float* item_emb = (const float*)d_in[1];
  const float* edge_val = (const float*)d_in[2];
  const float* W        = (const float*)d_in[3];
  const float* b        = (const float*)d_in[4];
  const int* edge_row   = (const int*)d_in[5];
  const int* edge_col   = (const int*)d_in[6];
  const int* bu         = (const int*)d_in[7];
  const int* bp         = (const int*)d_in[8];
  const int* bn         = (const int*)d_in[9];

  float* out = (float*)d_out;
  int* ws = (int*)d_ws;
  int*  cnt    = ws + WS_CNT;
  int*  off    = ws + WS_OFF;
  int*  cursor = ws + WS_CUR;
  int*  bsum   = ws + WS_BSUM;
  float* acc   = (float*)(ws + WS_ACC);
  int2* csr    = (int2*)(ws + WS_CSR);

  hipMemsetAsync(cnt, 0, 150016 * sizeof(int), stream);
  hipMemsetAsync(acc, 0, 2 * sizeof(float), stream);

  hist_kernel<<<(N_EDGES_C + 255) / 256, 256, 0, stream>>>(edge_row, edge_col, cnt);
  scan1_kernel<<<SCAN_NB, 256, 0, stream>>>(cnt, off, bsum);
  scan2_kernel<<<1, 64, 0, stream>>>(bsum);
  scan3_kernel<<<SCAN_NB, 256, 0, stream>>>(off, cursor, bsum);
  csr_scatter_kernel<<<(N_EDGES_C + 255) / 256, 256, 0, stream>>>(
      edge_row, edge_col, edge_val, cursor, csr);
  fused_kernel<<<(N_NODES_C + 31) / 32, 256, 0, stream>>>(
      user_emb, item_emb, W, b, off, csr, out);
  loss_kernel<<<BATCH_C / 4, 256, 0, stream>>>(out, bu, bp, bn, acc);
  finalize_kernel<<<1, 1, 0, stream>>>(acc, out);
}